// Round 13
// baseline (214.083 us; speedup 1.0000x reference)
//
#include <hip/hip_runtime.h>
#include <math.h>

#define CC   256      // channels
#define CR   16       // reduced channels
#define SB   16384    // H*W
#define NB   16       // batch
#define NG   32       // channel groups (8 ch each) for logit partials
#define NCHUNK 64     // softmax chunks per batch (256 s each)
#define CHSZ  256
#define ST   64       // (fallback) spatial tile
#define NT   (SB/ST)  // (fallback) tiles per batch
#define LN_EPS 1e-5f

typedef float          vfloat4  __attribute__((ext_vector_type(4)));
typedef unsigned short vushort4 __attribute__((ext_vector_type(4)));

__device__ __forceinline__ unsigned short f2b(float f) {
    unsigned int u;
    __builtin_memcpy(&u, &f, 4);
    unsigned int lsb = (u >> 16) & 1u;          // round-to-nearest-even bf16
    u += 0x7fffu + lsb;
    return (unsigned short)(u >> 16);
}
__device__ __forceinline__ float b2f(unsigned short u) {
    unsigned int v = ((unsigned int)u) << 16;
    float f;
    __builtin_memcpy(&f, &v, 4);
    return f;
}

// ---------------------------------------------------------------------------
// K1: block (b, g in 0..31, h in 0..1) owns 8 half-rows (32-KiB runs each).
// Reads x sequentially, accumulates 8-ch logit partials in 8 float4 regs,
// writes bf16 shadow (PLAIN x-layout, same offsets) + part[b][g][s-half].
// All streams sequential / >=32-KiB runs. grid: 1024 blocks, 256 threads.
// ---------------------------------------------------------------------------
__global__ __launch_bounds__(256) void k1_part_shadow(const float* __restrict__ x,
                                                      const float* __restrict__ w_mask,
                                                      unsigned short* __restrict__ shadow,
                                                      float* __restrict__ part) {
    const int t   = threadIdx.x;
    const int bid = blockIdx.x;
    const int h   = bid & 1;
    const int g   = (bid >> 1) & (NG - 1);
    const int b   = bid >> 6;

    __shared__ float wm[8];
    if (t < 8) wm[t] = w_mask[g * 8 + t];
    __syncthreads();

    const size_t base = ((size_t)b * CC + g * 8) * SB + h * 8192 + t * 4;

    vfloat4 acc[8];
#pragma unroll
    for (int j = 0; j < 8; ++j) acc[j] = (vfloat4){0.f, 0.f, 0.f, 0.f};

#pragma unroll
    for (int c = 0; c < 8; ++c) {
        const float w = wm[c];
        const float* rp = x + base + (size_t)c * SB;
        vfloat4 v[8];
#pragma unroll
        for (int j = 0; j < 8; ++j)
            v[j] = *reinterpret_cast<const vfloat4*>(rp + j * 1024);
#pragma unroll
        for (int j = 0; j < 8; ++j)
            acc[j] += v[j] * w;
        unsigned short* sp = shadow + base + (size_t)c * SB;
#pragma unroll
        for (int j = 0; j < 8; ++j) {
            vushort4 u = { f2b(v[j].x), f2b(v[j].y), f2b(v[j].z), f2b(v[j].w) };
            *reinterpret_cast<vushort4*>(sp + j * 1024) = u;
        }
    }

    float* pp = part + ((size_t)b * NG + g) * SB + h * 8192 + t * 4;
#pragma unroll
    for (int j = 0; j < 8; ++j)
        *reinterpret_cast<vfloat4*>(pp + j * 1024) = acc[j];
}

// ---------------------------------------------------------------------------
// K2: logits = sum of 32 group partials per s; per-256-chunk softmax
// numerator + chunk max/sum. grid: 16*64 = 1024 blocks.
// ---------------------------------------------------------------------------
__global__ __launch_bounds__(256) void k2_chunks(const float* __restrict__ part,
                                                 float* __restrict__ pl_num,
                                                 float* __restrict__ pm,
                                                 float* __restrict__ ps) {
    const int t  = threadIdx.x;
    const int b  = blockIdx.x >> 6;
    const int ch = blockIdx.x & 63;
    __shared__ float red[256];

    const int s = ch * CHSZ + t;
    float l = 0.f;
#pragma unroll 8
    for (int g = 0; g < NG; ++g)
        l += part[((size_t)b * NG + g) * SB + s];

    red[t] = l; __syncthreads();
    for (int st = 128; st > 0; st >>= 1) {
        if (t < st) red[t] = fmaxf(red[t], red[t + st]);
        __syncthreads();
    }
    const float mc = red[0]; __syncthreads();

    const float p = __expf(l - mc);
    pl_num[(size_t)b * SB + s] = p;

    red[t] = p; __syncthreads();
    for (int st = 128; st > 0; st >>= 1) {
        if (t < st) red[t] += red[t + st];
        __syncthreads();
    }
    if (t == 0) { pm[b * NCHUNK + ch] = mc; ps[b * NCHUNK + ch] = red[0]; }
}

// ---------------------------------------------------------------------------
// K3: context partials. Block (b,g,h): reads 8 bf16 half-rows (16-KiB runs)
// + pl_num half (float4); 8 scalar accs -> shuffle+LDS reduce -> 8 floats.
// Flash combine factors recomputed on wave 0 (512 B from L2).
// grid: 1024 blocks.
// ---------------------------------------------------------------------------
__global__ __launch_bounds__(256) void k3_context(const unsigned short* __restrict__ shadow,
                                                  const float* __restrict__ pl_num,
                                                  const float* __restrict__ pm,
                                                  const float* __restrict__ ps,
                                                  float* __restrict__ ctxp) {
    const int t   = threadIdx.x;
    const int bid = blockIdx.x;
    const int h   = bid & 1;
    const int g   = (bid >> 1) & (NG - 1);
    const int b   = bid >> 6;

    __shared__ float fxs[NCHUNK];
    __shared__ float wred[4][8];

    if (t < NCHUNK) {                 // wave 0: exact flash combine
        const float m_t = pm[b * NCHUNK + t];
        float M = m_t;
#pragma unroll
        for (int off = 32; off > 0; off >>= 1)
            M = fmaxf(M, __shfl_xor(M, off));
        const float f = __expf(m_t - M);
        float z = ps[b * NCHUNK + t] * f;
#pragma unroll
        for (int off = 32; off > 0; off >>= 1)
            z += __shfl_xor(z, off);
        fxs[t] = f / z;
    }
    __syncthreads();

    const size_t base = ((size_t)b * CC + g * 8) * SB + h * 8192 + t * 4;
    const float* pn = pl_num + (size_t)b * SB + h * 8192 + t * 4;

    float acc[8];
#pragma unroll
    for (int c = 0; c < 8; ++c) acc[c] = 0.f;

#pragma unroll
    for (int j = 0; j < 8; ++j) {
        vfloat4 p = *reinterpret_cast<const vfloat4*>(pn + j * 1024);
        const float f = fxs[h * 32 + j * 4 + (t >> 6)];   // uniform per wave
        p *= f;
#pragma unroll
        for (int c = 0; c < 8; ++c) {
            const ushort4 u = *reinterpret_cast<const ushort4*>(shadow + base + (size_t)c * SB + j * 1024);
            acc[c] += b2f(u.x) * p.x + b2f(u.y) * p.y + b2f(u.z) * p.z + b2f(u.w) * p.w;
        }
    }
#pragma unroll
    for (int c = 0; c < 8; ++c) {
#pragma unroll
        for (int off = 32; off > 0; off >>= 1)
            acc[c] += __shfl_xor(acc[c], off);
    }
    const int wv = t >> 6;
    if ((t & 63) == 0) {
#pragma unroll
        for (int c = 0; c < 8; ++c) wred[wv][c] = acc[c];
    }
    __syncthreads();
    if (t < 8)
        ctxp[(((size_t)b * NG + g) * 2 + h) * 8 + t] =
            wred[0][t] + wred[1][t] + wred[2][t] + wred[3][t];
}

// ---------------------------------------------------------------------------
// K4: reduce ctxp over halves + tiny MLP. grid: 16 blocks, 256 threads.
// ---------------------------------------------------------------------------
__global__ __launch_bounds__(256) void k4_mlp(const float* __restrict__ ctxp,
                                              const float* __restrict__ w1,
                                              const float* __restrict__ b1,
                                              const float* __restrict__ ln_g,
                                              const float* __restrict__ ln_b,
                                              const float* __restrict__ w2,
                                              const float* __restrict__ b2,
                                              float* __restrict__ add) {
    const int b = blockIdx.x;
    const int t = threadIdx.x;
    __shared__ float cx[CC];
    __shared__ float tbuf[CR];
    __shared__ float tn[CR];

    {   // t = g*8 + c
        const int g = t >> 3, c = t & 7;
        cx[t] = ctxp[(((size_t)b * NG + g) * 2 + 0) * 8 + c]
              + ctxp[(((size_t)b * NG + g) * 2 + 1) * 8 + c];
    }
    __syncthreads();

    if (t < CR) {
        float a = b1[t];
        const float* w1r = w1 + (size_t)t * CC;
#pragma unroll 8
        for (int c = 0; c < CC; ++c) a += w1r[c] * cx[c];
        tbuf[t] = a;
    }
    __syncthreads();
    if (t == 0) {
        float mu = 0.f;
        for (int q = 0; q < CR; ++q) mu += tbuf[q];
        mu *= (1.0f / CR);
        float var = 0.f;
        for (int q = 0; q < CR; ++q) { const float d = tbuf[q] - mu; var += d * d; }
        var *= (1.0f / CR);
        const float inv = rsqrtf(var + LN_EPS);
        for (int q = 0; q < CR; ++q) {
            const float v = (tbuf[q] - mu) * inv * ln_g[q] + ln_b[q];
            tn[q] = v > 0.f ? v : 0.f;
        }
    }
    __syncthreads();

    float a = b2[t];
    const float* w2r = w2 + (size_t)t * CR;
#pragma unroll
    for (int o = 0; o < CR; ++o) a += w2r[o] * tn[o];
    add[(size_t)b * CC + t] = a;
}

// ---------------------------------------------------------------------------
// K5: out = bf16shadow + add. Shadow is plain x-layout -> identical linear
// indexing; pure sequential read + nt-store write. grid: 32768 blocks.
// ---------------------------------------------------------------------------
__global__ __launch_bounds__(256) void k5_add(const unsigned short* __restrict__ shadow,
                                              const float* __restrict__ add,
                                              float* __restrict__ out) {
    const size_t idx = ((size_t)blockIdx.x * 256 + threadIdx.x) * 8;
    const size_t bc = idx / SB;
    const float a = add[bc];
    const uint4 d = *reinterpret_cast<const uint4*>(shadow + idx);
    vfloat4 o0 = {b2f(d.x & 0xffffu) + a, b2f(d.x >> 16) + a,
                  b2f(d.y & 0xffffu) + a, b2f(d.y >> 16) + a};
    vfloat4 o1 = {b2f(d.z & 0xffffu) + a, b2f(d.z >> 16) + a,
                  b2f(d.w & 0xffffu) + a, b2f(d.w >> 16) + a};
    __builtin_nontemporal_store(o0, reinterpret_cast<vfloat4*>(out + idx));
    __builtin_nontemporal_store(o1, reinterpret_cast<vfloat4*>(out + idx + 4));
}

// ===========================================================================
// Fallback (round-7 proven 170 us), used only if ws_size is too small.
// ===========================================================================
__global__ __launch_bounds__(256) void f_ctx_partial(const float* __restrict__ x,
                                                     const float* __restrict__ w_mask,
                                                     float* __restrict__ pc,
                                                     float* __restrict__ pm,
                                                     float* __restrict__ ps) {
    __shared__ float plog[ST * 5];
    __shared__ float pl[ST];
    __shared__ float wm[CC];
    __shared__ float red2[CC * 17];

    const int t   = threadIdx.x;
    const int bid = blockIdx.x;
    const int b   = bid / NT;
    const int s0  = (bid % NT) * ST;

    wm[t] = w_mask[t];
    __syncthreads();

    const int g  = t >> 4;
    const int i  = t & 15;
    const int s4 = i << 2;

    const float* xb = x + (size_t)b * CC * SB + s0 + s4;
    float4 v[16];
    float4 acc = make_float4(0.f, 0.f, 0.f, 0.f);
#pragma unroll
    for (int k = 0; k < 16; ++k) {
        const int c = g + (k << 4);
        v[k] = *reinterpret_cast<const float4*>(xb + (size_t)c * SB);
        const float w = wm[c];
        acc.x += v[k].x * w; acc.y += v[k].y * w;
        acc.z += v[k].z * w; acc.w += v[k].w * w;
    }
    acc.x += __shfl_xor(acc.x, 16); acc.y += __shfl_xor(acc.y, 16);
    acc.z += __shfl_xor(acc.z, 16); acc.w += __shfl_xor(acc.w, 16);
    acc.x += __shfl_xor(acc.x, 32); acc.y += __shfl_xor(acc.y, 32);
    acc.z += __shfl_xor(acc.z, 32); acc.w += __shfl_xor(acc.w, 32);
    const int wv = t >> 6;
    if ((t & 63) < 16) {
        plog[(s4 + 0) * 5 + wv] = acc.x;
        plog[(s4 + 1) * 5 + wv] = acc.y;
        plog[(s4 + 2) * 5 + wv] = acc.z;
        plog[(s4 + 3) * 5 + wv] = acc.w;
    }
    __syncthreads();

    if (t < ST) {
        const float logit = plog[t * 5 + 0] + plog[t * 5 + 1]
                          + plog[t * 5 + 2] + plog[t * 5 + 3];
        float m = logit;
#pragma unroll
        for (int off = 32; off > 0; off >>= 1)
            m = fmaxf(m, __shfl_xor(m, off));
        const float p = __expf(logit - m);
        pl[t] = p;
        float sum = p;
#pragma unroll
        for (int off = 32; off > 0; off >>= 1)
            sum += __shfl_xor(sum, off);
        if (t == 0) { pm[bid] = m; ps[bid] = sum; }
    }
    __syncthreads();

    const float p0 = pl[s4 + 0], p1 = pl[s4 + 1];
    const float p2 = pl[s4 + 2], p3 = pl[s4 + 3];
#pragma unroll
    for (int k = 0; k < 16; ++k) {
        const int c = g + (k << 4);
        red2[c * 17 + i] = v[k].x * p0 + v[k].y * p1 + v[k].z * p2 + v[k].w * p3;
    }
    __syncthreads();
    float s = 0.f;
#pragma unroll
    for (int j = 0; j < 16; ++j) s += red2[t * 17 + j];
    pc[(size_t)bid * CC + t] = s;
}

__global__ __launch_bounds__(256) void f_combine_mlp(const float* __restrict__ pc,
                                                     const float* __restrict__ pm,
                                                     const float* __restrict__ ps,
                                                     const float* __restrict__ w1,
                                                     const float* __restrict__ b1,
                                                     const float* __restrict__ ln_g,
                                                     const float* __restrict__ ln_b,
                                                     const float* __restrict__ w2,
                                                     const float* __restrict__ b2,
                                                     float* __restrict__ add) {
    const int b = blockIdx.x;
    const int t = threadIdx.x;
    __shared__ float red[256];
    __shared__ float fx[NT];
    __shared__ float ctx[CC];
    __shared__ float tbuf[CR];
    __shared__ float tn[CR];

    const float m_t = pm[b * NT + t];
    red[t] = m_t; __syncthreads();
    for (int st = 128; st > 0; st >>= 1) {
        if (t < st) red[t] = fmaxf(red[t], red[t + st]);
        __syncthreads();
    }
    const float M = red[0]; __syncthreads();

    const float f = __expf(m_t - M);
    fx[t] = f;
    red[t] = ps[b * NT + t] * f; __syncthreads();
    for (int st = 128; st > 0; st >>= 1) {
        if (t < st) red[t] += red[t + st];
        __syncthreads();
    }
    const float invZ = 1.0f / red[0]; __syncthreads();

    float acc = 0.f;
#pragma unroll 4
    for (int j = 0; j < NT; ++j)
        acc += pc[((size_t)b * NT + j) * CC + t] * fx[j];
    ctx[t] = acc * invZ;
    __syncthreads();

    if (t < CR) {
        float a = b1[t];
        const float* w1r = w1 + (size_t)t * CC;
#pragma unroll 8
        for (int c = 0; c < CC; ++c) a += w1r[c] * ctx[c];
        tbuf[t] = a;
    }
    __syncthreads();
    if (t == 0) {
        float mu = 0.f;
        for (int i = 0; i < CR; ++i) mu += tbuf[i];
        mu *= (1.0f / CR);
        float var = 0.f;
        for (int i = 0; i < CR; ++i) { const float d = tbuf[i] - mu; var += d * d; }
        var *= (1.0f / CR);
        const float inv = rsqrtf(var + LN_EPS);
        for (int i = 0; i < CR; ++i) {
            const float v = (tbuf[i] - mu) * inv * ln_g[i] + ln_b[i];
            tn[i] = v > 0.f ? v : 0.f;
        }
    }
    __syncthreads();

    float a = b2[t];
    const float* w2r = w2 + (size_t)t * CR;
#pragma unroll
    for (int o = 0; o < CR; ++o) a += w2r[o] * tn[o];
    add[(size_t)b * CC + t] = a;
}

__global__ __launch_bounds__(256) void f_add(const float* __restrict__ x,
                                             const float* __restrict__ add,
                                             float* __restrict__ out) {
    const size_t idx = ((size_t)blockIdx.x * 256 + threadIdx.x) * 8;
    const size_t bc = idx / SB;
    const float a = add[bc];
    const float4 v0 = *reinterpret_cast<const float4*>(x + idx);
    const float4 v1 = *reinterpret_cast<const float4*>(x + idx + 4);
    vfloat4 o0 = {v0.x + a, v0.y + a, v0.z + a, v0.w + a};
    vfloat4 o1 = {v1.x + a, v1.y + a, v1.z + a, v1.w + a};
    __builtin_nontemporal_store(o0, reinterpret_cast<vfloat4*>(out + idx));
    __builtin_nontemporal_store(o1, reinterpret_cast<vfloat4*>(out + idx + 4));
}

// ---------------------------------------------------------------------------
extern "C" void kernel_launch(void* const* d_in, const int* in_sizes, int n_in,
                              void* d_out, int out_size, void* d_ws, size_t ws_size,
                              hipStream_t stream) {
    const float* x      = (const float*)d_in[0];
    const float* w_mask = (const float*)d_in[1];
    // d_in[2] = b_mask: scalar added to all logits; cancels in softmax.
    const float* w1     = (const float*)d_in[3];
    const float* b1     = (const float*)d_in[4];
    const float* ln_g   = (const float*)d_in[5];
    const float* ln_b   = (const float*)d_in[6];
    const float* w2     = (const float*)d_in[7];
    const float* b2     = (const float*)d_in[8];
    float* out = (float*)d_out;

    const size_t nx = (size_t)NB * CC * SB;           // 67,108,864
    unsigned short* shadow = (unsigned short*)d_ws;   // 128 MiB, plain x-layout
    float* fbase  = (float*)((char*)d_ws + nx * sizeof(unsigned short));
    float* part   = fbase;                            // NB*NG*SB = 32 MiB
    float* pl_num = part + (size_t)NB * NG * SB;      // 1 MiB
    float* pm     = pl_num + (size_t)NB * SB;
    float* ps     = pm + NB * NCHUNK;
    float* ctxp   = ps + NB * NCHUNK;                 // NB*NG*2*8 = 8192
    float* add    = ctxp + (size_t)NB * NG * 2 * 8;
    const size_t need = (size_t)((char*)(add + (size_t)NB * CC) - (char*)d_ws);

    if (ws_size >= need) {
        k1_part_shadow<<<dim3(1024), dim3(256), 0, stream>>>(x, w_mask, shadow, part);
        k2_chunks<<<dim3(NB * NCHUNK), dim3(256), 0, stream>>>(part, pl_num, pm, ps);
        k3_context<<<dim3(1024), dim3(256), 0, stream>>>(shadow, pl_num, pm, ps, ctxp);
        k4_mlp<<<dim3(NB), dim3(256), 0, stream>>>(ctxp, w1, b1, ln_g, ln_b, w2, b2, add);
        k5_add<<<dim3(32768), dim3(256), 0, stream>>>(shadow, add, out);
    } else {
        float* pc  = (float*)d_ws;
        float* fpm = pc + (size_t)NB * NT * CC;
        float* fps = fpm + (size_t)NB * NT;
        float* fad = fps + (size_t)NB * NT;
        f_ctx_partial<<<dim3(NB * NT), dim3(256), 0, stream>>>(x, w_mask, pc, fpm, fps);
        f_combine_mlp<<<dim3(NB), dim3(256), 0, stream>>>(pc, fpm, fps, w1, b1, ln_g, ln_b, w2, b2, fad);
        f_add<<<dim3(NB * CC * SB / 2048), dim3(256), 0, stream>>>(x, fad, out);
    }
}

// Round 14
// 185.086 us; speedup vs baseline: 1.1567x; 1.1567x over previous
//
#include <hip/hip_runtime.h>
#include <math.h>

#define CC   256      // channels
#define CR   16       // reduced channels
#define SB   16384    // H*W
#define NB   16       // batch
#define SQ   256      // s-positions per chunk/block (kernel A)
#define NQ   (SB/SQ)  // 64 chunks per batch
#define LN_EPS 1e-5f

typedef float vfloat4 __attribute__((ext_vector_type(4)));

// ---------------------------------------------------------------------------
// Kernel A: block (b, sq-chunk of 256 s), 1024 threads = 16 waves.
// Wave w owns channels 16w..16w+15; lane l owns s = sq*256 + 4l..+3.
// Each global load = 64 lanes x 16 B = 1-KiB contiguous run per channel
// (4x the run length of the previous 256-thread mapping -> DRAM row-friendly).
// x tile (256 KiB) stays in 16 float4 registers/thread; logit partial fused
// into staging; chunk softmax (exact flash pieces pm/ps); context partials
// from registers via wave-internal shuffle reduce (lanes = the 64 s-slots).
// b_mask is a scalar on all logits -> cancels in softmax -> dropped.
// grid: NB*NQ = 1024 blocks.
// ---------------------------------------------------------------------------
__global__ __launch_bounds__(1024) void k_ctx(const float* __restrict__ x,
                                              const float* __restrict__ w_mask,
                                              float* __restrict__ pc,
                                              float* __restrict__ pm,
                                              float* __restrict__ ps) {
    __shared__ float wm[CC];
    __shared__ float plog[SQ * 17];   // [s][wave] padded, 17.4 KiB
    __shared__ float red[SQ];
    __shared__ float pl[SQ];

    const int t   = threadIdx.x;
    const int bid = blockIdx.x;
    const int b   = bid >> 6;
    const int sq  = bid & 63;

    if (t < CC) wm[t] = w_mask[t];
    __syncthreads();

    const int w  = t >> 6;            // wave = channel group 0..15
    const int l  = t & 63;            // lane = s-slot
    const int s4 = l << 2;

    // stage 16 channels x 4 s into registers + fused logit partial
    const float* xb = x + ((size_t)(b * CC + w * 16)) * SB + sq * SQ + s4;
    vfloat4 v[16];
    float ax = 0.f, ay = 0.f, az = 0.f, aw = 0.f;
#pragma unroll
    for (int k = 0; k < 16; ++k) {
        v[k] = *reinterpret_cast<const vfloat4*>(xb + (size_t)k * SB);
        const float wt = wm[w * 16 + k];
        ax += wt * v[k].x; ay += wt * v[k].y; az += wt * v[k].z; aw += wt * v[k].w;
    }
    plog[(s4 + 0) * 17 + w] = ax;
    plog[(s4 + 1) * 17 + w] = ay;
    plog[(s4 + 2) * 17 + w] = az;
    plog[(s4 + 3) * 17 + w] = aw;
    __syncthreads();

    // finalize logits (threads 0..255, one per s) + chunk softmax
    float logit = 0.f;
    if (t < SQ) {
#pragma unroll
        for (int i = 0; i < 16; ++i) logit += plog[t * 17 + i];
        red[t] = logit;
    }
    __syncthreads();
    for (int st = 128; st > 0; st >>= 1) {
        if (t < st) red[t] = fmaxf(red[t], red[t + st]);
        __syncthreads();
    }
    const float mc = red[0];
    __syncthreads();
    if (t < SQ) {
        const float p = __expf(logit - mc);
        pl[t] = p; red[t] = p;
    }
    __syncthreads();
    for (int st = 128; st > 0; st >>= 1) {
        if (t < st) red[t] += red[t + st];
        __syncthreads();
    }
    if (t == 0) { pm[bid] = mc; ps[bid] = red[0]; }
    __syncthreads();

    // context partials from registers; wave-reduce over the 64 s-lanes
    const vfloat4 p = *reinterpret_cast<const vfloat4*>(&pl[s4]);
#pragma unroll
    for (int k = 0; k < 16; ++k) {
        float a = v[k].x * p.x + v[k].y * p.y + v[k].z * p.z + v[k].w * p.w;
#pragma unroll
        for (int off = 32; off > 0; off >>= 1)
            a += __shfl_xor(a, off);
        if (l == 0) pc[(size_t)bid * CC + w * 16 + k] = a;
    }
}

// ---------------------------------------------------------------------------
// Kernel B: flash-combine across NQ=64 chunks per batch + full MLP.
// grid: NB blocks, 256 threads.
// ---------------------------------------------------------------------------
__global__ __launch_bounds__(256) void k_combine_mlp(const float* __restrict__ pc,
                                                     const float* __restrict__ pm,
                                                     const float* __restrict__ ps,
                                                     const float* __restrict__ w1,
                                                     const float* __restrict__ b1,
                                                     const float* __restrict__ ln_g,
                                                     const float* __restrict__ ln_b,
                                                     const float* __restrict__ w2,
                                                     const float* __restrict__ b2,
                                                     float* __restrict__ add) {
    const int b = blockIdx.x;
    const int t = threadIdx.x;
    __shared__ float fxs[NQ];
    __shared__ float ctx[CC];
    __shared__ float tbuf[CR];
    __shared__ float tn[CR];

    if (t < NQ) {   // one wave: exact combine factors
        const float m_t = pm[b * NQ + t];
        float M = m_t;
#pragma unroll
        for (int off = 32; off > 0; off >>= 1)
            M = fmaxf(M, __shfl_xor(M, off));
        const float f = __expf(m_t - M);
        float z = ps[b * NQ + t] * f;
#pragma unroll
        for (int off = 32; off > 0; off >>= 1)
            z += __shfl_xor(z, off);
        fxs[t] = f / z;
    }
    __syncthreads();

    // ctx[c] = sum_chunks pc[chunk][c] * fxs[chunk]  (coalesced over c=t)
    float acc = 0.f;
#pragma unroll 4
    for (int q = 0; q < NQ; ++q)
        acc += pc[((size_t)b * NQ + q) * CC + t] * fxs[q];
    ctx[t] = acc;
    __syncthreads();

    if (t < CR) {
        float a = b1[t];
        const float* w1r = w1 + (size_t)t * CC;
#pragma unroll 8
        for (int c = 0; c < CC; ++c) a += w1r[c] * ctx[c];
        tbuf[t] = a;
    }
    __syncthreads();
    if (t == 0) {
        float mu = 0.f;
        for (int q = 0; q < CR; ++q) mu += tbuf[q];
        mu *= (1.0f / CR);
        float var = 0.f;
        for (int q = 0; q < CR; ++q) { const float d = tbuf[q] - mu; var += d * d; }
        var *= (1.0f / CR);
        const float inv = rsqrtf(var + LN_EPS);
        for (int q = 0; q < CR; ++q) {
            const float v = (tbuf[q] - mu) * inv * ln_g[q] + ln_b[q];
            tn[q] = v > 0.f ? v : 0.f;
        }
    }
    __syncthreads();

    float a = b2[t];
    const float* w2r = w2 + (size_t)t * CR;
#pragma unroll
    for (int o = 0; o < CR; ++o) a += w2r[o] * tn[o];
    add[(size_t)b * CC + t] = a;
}

// ---------------------------------------------------------------------------
// Kernel C: out[b,c,s] = x[b,c,s] + add[b,c]. Pure sequential stream,
// nt-stores. 8 floats/thread, grid: 32768 blocks. (proven ~85 us)
// ---------------------------------------------------------------------------
__global__ __launch_bounds__(256) void k_add(const float* __restrict__ x,
                                             const float* __restrict__ add,
                                             float* __restrict__ out) {
    const size_t idx = ((size_t)blockIdx.x * 256 + threadIdx.x) * 8;
    const size_t bc = idx / SB;
    const float a = add[bc];
    const float4 v0 = *reinterpret_cast<const float4*>(x + idx);
    const float4 v1 = *reinterpret_cast<const float4*>(x + idx + 4);
    vfloat4 o0 = {v0.x + a, v0.y + a, v0.z + a, v0.w + a};
    vfloat4 o1 = {v1.x + a, v1.y + a, v1.z + a, v1.w + a};
    __builtin_nontemporal_store(o0, reinterpret_cast<vfloat4*>(out + idx));
    __builtin_nontemporal_store(o1, reinterpret_cast<vfloat4*>(out + idx + 4));
}

// ---------------------------------------------------------------------------
extern "C" void kernel_launch(void* const* d_in, const int* in_sizes, int n_in,
                              void* d_out, int out_size, void* d_ws, size_t ws_size,
                              hipStream_t stream) {
    const float* x      = (const float*)d_in[0];
    const float* w_mask = (const float*)d_in[1];
    // d_in[2] = b_mask: scalar added to all logits; cancels in softmax.
    const float* w1     = (const float*)d_in[3];
    const float* b1     = (const float*)d_in[4];
    const float* ln_g   = (const float*)d_in[5];
    const float* ln_b   = (const float*)d_in[6];
    const float* w2     = (const float*)d_in[7];
    const float* b2     = (const float*)d_in[8];
    float* out = (float*)d_out;

    // workspace: pc[NB*NQ*CC] = 262144 floats (1 MiB), pm/ps[NB*NQ], add
    float* ws  = (float*)d_ws;
    float* pc  = ws;
    float* pm  = pc + (size_t)NB * NQ * CC;
    float* ps  = pm + (size_t)NB * NQ;
    float* add = ps + (size_t)NB * NQ;

    k_ctx<<<dim3(NB * NQ), dim3(1024), 0, stream>>>(x, w_mask, pc, pm, ps);
    k_combine_mlp<<<dim3(NB), dim3(256), 0, stream>>>(pc, pm, ps, w1, b1, ln_g, ln_b, w2, b2, add);
    k_add<<<dim3(NB * CC * SB / 2048), dim3(256), 0, stream>>>(x, add, out);
}

// Round 15
// 171.238 us; speedup vs baseline: 1.2502x; 1.0809x over previous
//
#include <hip/hip_runtime.h>
#include <math.h>

#define CC   256      // channels
#define CR   16       // reduced channels
#define SB   16384    // H*W
#define NB   16       // batch
#define ST   64       // spatial tile per block
#define NT   (SB/ST)  // 256 tiles per batch
#define LN_EPS 1e-5f

typedef float vfloat4 __attribute__((ext_vector_type(4)));  // builtin-compatible

// ---------------------------------------------------------------------------
// Kernel A (fused, register-resident) — round-7 best configuration.
// One 64-position spatial tile per block, 256 threads. Thread t holds
// channels c = (t>>4) + 16k (k=0..15) at s4 = (t&15)*4 in 16 float4
// REGISTERS. Logit partial fused into staging; tile softmax numerator via
// wave-0 shuffles; context partial from registers through a padded LDS
// reduce. b_mask is a scalar on all logits -> cancels in softmax -> dropped.
// grid: NB*NT = 4096 blocks. LDS ~19 KiB, VGPR ~100.
// A runs at the empirical strided-read ceiling (~3.2 TB/s): occupancy (r6),
// LDS structure (r7), run length (r14), shadow/bf16 (r10-13), cooperative
// single-read (r9) all failed to move it.
// ---------------------------------------------------------------------------
__global__ __launch_bounds__(256) void k_ctx_partial(const float* __restrict__ x,
                                                     const float* __restrict__ w_mask,
                                                     float* __restrict__ pc,
                                                     float* __restrict__ pm,
                                                     float* __restrict__ ps) {
    __shared__ float plog[ST * 5];      // logit partials [s][wave 0..3], pad 5
    __shared__ float pl[ST];            // exp(l - m) per s
    __shared__ float wm[CC];            // w_mask copy
    __shared__ float red2[CC * 17];     // context partials [c][group], pad 17

    const int t   = threadIdx.x;
    const int bid = blockIdx.x;
    const int b   = bid / NT;
    const int s0  = (bid % NT) * ST;

    wm[t] = w_mask[t];
    __syncthreads();

    const int g  = t >> 4;              // channel-group base 0..15
    const int i  = t & 15;              // s4 slot 0..15
    const int s4 = i << 2;

    // stage into registers + fused logit partial
    const float* xb = x + (size_t)b * CC * SB + s0 + s4;
    float4 v[16];
    float4 acc = make_float4(0.f, 0.f, 0.f, 0.f);
#pragma unroll
    for (int k = 0; k < 16; ++k) {
        const int c = g + (k << 4);
        v[k] = *reinterpret_cast<const float4*>(xb + (size_t)c * SB);
        const float w = wm[c];
        acc.x += v[k].x * w; acc.y += v[k].y * w;
        acc.z += v[k].z * w; acc.w += v[k].w * w;
    }
    // reduce logit partial across the 4 lanes sharing s4 within this wave
    acc.x += __shfl_xor(acc.x, 16); acc.y += __shfl_xor(acc.y, 16);
    acc.z += __shfl_xor(acc.z, 16); acc.w += __shfl_xor(acc.w, 16);
    acc.x += __shfl_xor(acc.x, 32); acc.y += __shfl_xor(acc.y, 32);
    acc.z += __shfl_xor(acc.z, 32); acc.w += __shfl_xor(acc.w, 32);
    const int wv = t >> 6;              // wave 0..3
    if ((t & 63) < 16) {
        plog[(s4 + 0) * 5 + wv] = acc.x;
        plog[(s4 + 1) * 5 + wv] = acc.y;
        plog[(s4 + 2) * 5 + wv] = acc.z;
        plog[(s4 + 3) * 5 + wv] = acc.w;
    }
    __syncthreads();

    // finalize logits + tile softmax numerator on wave 0
    if (t < ST) {
        const float logit = plog[t * 5 + 0] + plog[t * 5 + 1]
                          + plog[t * 5 + 2] + plog[t * 5 + 3];
        float m = logit;
#pragma unroll
        for (int off = 32; off > 0; off >>= 1)
            m = fmaxf(m, __shfl_xor(m, off));
        const float p = __expf(logit - m);
        pl[t] = p;
        float sum = p;
#pragma unroll
        for (int off = 32; off > 0; off >>= 1)
            sum += __shfl_xor(sum, off);
        if (t == 0) { pm[bid] = m; ps[bid] = sum; }
    }
    __syncthreads();

    // context partials straight from registers
    const float p0 = pl[s4 + 0], p1 = pl[s4 + 1];
    const float p2 = pl[s4 + 2], p3 = pl[s4 + 3];
#pragma unroll
    for (int k = 0; k < 16; ++k) {
        const int c = g + (k << 4);
        red2[c * 17 + i] = v[k].x * p0 + v[k].y * p1 + v[k].z * p2 + v[k].w * p3;
    }
    __syncthreads();

    // final 16-way sum per channel (t = channel), stride-17 -> conflict-free
    float s = 0.f;
#pragma unroll
    for (int j = 0; j < 16; ++j) s += red2[t * 17 + j];
    pc[(size_t)bid * CC + t] = s;
}

// ---------------------------------------------------------------------------
// Kernel B: flash-combine across NT=256 tiles per batch + full MLP.
// grid: NB blocks, 256 threads.
// ---------------------------------------------------------------------------
__global__ __launch_bounds__(256) void k_combine_mlp(const float* __restrict__ pc,
                                                     const float* __restrict__ pm,
                                                     const float* __restrict__ ps,
                                                     const float* __restrict__ w1,
                                                     const float* __restrict__ b1,
                                                     const float* __restrict__ ln_g,
                                                     const float* __restrict__ ln_b,
                                                     const float* __restrict__ w2,
                                                     const float* __restrict__ b2,
                                                     float* __restrict__ add) {
    const int b = blockIdx.x;
    const int t = threadIdx.x;
    __shared__ float red[256];
    __shared__ float fx[NT];
    __shared__ float ctx[CC];
    __shared__ float tbuf[CR];
    __shared__ float tn[CR];

    // global max over tile maxima
    const float m_t = pm[b * NT + t];
    red[t] = m_t; __syncthreads();
    for (int st = 128; st > 0; st >>= 1) {
        if (t < st) red[t] = fmaxf(red[t], red[t + st]);
        __syncthreads();
    }
    const float M = red[0]; __syncthreads();

    // rescale factors + global Z
    const float f = __expf(m_t - M);
    fx[t] = f;
    red[t] = ps[b * NT + t] * f; __syncthreads();
    for (int st = 128; st > 0; st >>= 1) {
        if (t < st) red[t] += red[t + st];
        __syncthreads();
    }
    const float invZ = 1.0f / red[0]; __syncthreads();

    // ctx[c] = sum_tiles pc[tile][c] * fx[tile] / Z   (coalesced over c=t)
    float acc = 0.f;
#pragma unroll 4
    for (int j = 0; j < NT; ++j)
        acc += pc[((size_t)b * NT + j) * CC + t] * fx[j];
    ctx[t] = acc * invZ;
    __syncthreads();

    // MLP: t1 = w1@ctx + b1 ; LN ; ReLU ; add = w2@t1 + b2
    if (t < CR) {
        float a = b1[t];
        const float* w1r = w1 + (size_t)t * CC;
#pragma unroll 8
        for (int c = 0; c < CC; ++c) a += w1r[c] * ctx[c];
        tbuf[t] = a;
    }
    __syncthreads();
    if (t == 0) {
        float mu = 0.f;
        for (int i = 0; i < CR; ++i) mu += tbuf[i];
        mu *= (1.0f / CR);
        float var = 0.f;
        for (int i = 0; i < CR; ++i) { const float d = tbuf[i] - mu; var += d * d; }
        var *= (1.0f / CR);
        const float inv = rsqrtf(var + LN_EPS);
        for (int i = 0; i < CR; ++i) {
            const float v = (tbuf[i] - mu) * inv * ln_g[i] + ln_b[i];
            tn[i] = v > 0.f ? v : 0.f;
        }
    }
    __syncthreads();

    float a = b2[t];
    const float* w2r = w2 + (size_t)t * CR;
#pragma unroll
    for (int o = 0; o < CR; ++o) a += w2r[o] * tn[o];
    add[(size_t)b * CC + t] = a;
}

// ---------------------------------------------------------------------------
// Kernel C: out[b,c,s] = x[b,c,s] + add[b,c]. Sequential stream at ~6.5 TB/s
// (~96% of achievable) — at roofline. nt-stores; 8 floats/thread.
// grid: 32768 blocks.
// ---------------------------------------------------------------------------
__global__ __launch_bounds__(256) void k_add(const float* __restrict__ x,
                                             const float* __restrict__ add,
                                             float* __restrict__ out) {
    const size_t idx = ((size_t)blockIdx.x * 256 + threadIdx.x) * 8;
    const size_t bc = idx / SB;   // 8 elems never cross a (b,c) boundary
    const float a = add[bc];
    const float4 v0 = *reinterpret_cast<const float4*>(x + idx);
    const float4 v1 = *reinterpret_cast<const float4*>(x + idx + 4);
    vfloat4 o0 = {v0.x + a, v0.y + a, v0.z + a, v0.w + a};
    vfloat4 o1 = {v1.x + a, v1.y + a, v1.z + a, v1.w + a};
    __builtin_nontemporal_store(o0, reinterpret_cast<vfloat4*>(out + idx));
    __builtin_nontemporal_store(o1, reinterpret_cast<vfloat4*>(out + idx + 4));
}

// ---------------------------------------------------------------------------
extern "C" void kernel_launch(void* const* d_in, const int* in_sizes, int n_in,
                              void* d_out, int out_size, void* d_ws, size_t ws_size,
                              hipStream_t stream) {
    const float* x      = (const float*)d_in[0];
    const float* w_mask = (const float*)d_in[1];
    // d_in[2] = b_mask: scalar added to all logits; cancels in softmax.
    const float* w1     = (const float*)d_in[3];
    const float* b1     = (const float*)d_in[4];
    const float* ln_g   = (const float*)d_in[5];
    const float* ln_b   = (const float*)d_in[6];
    const float* w2     = (const float*)d_in[7];
    const float* b2     = (const float*)d_in[8];
    float* out = (float*)d_out;

    // workspace (floats): pc[NB*NT*CC]=1M, pm/ps[NB*NT], add[NB*CC]
    float* ws  = (float*)d_ws;
    float* pc  = ws;                              // 1,048,576
    float* pm  = pc + (size_t)NB * NT * CC;       // 4096
    float* ps  = pm + (size_t)NB * NT;            // 4096
    float* add = ps + (size_t)NB * NT;            // 4096

    k_ctx_partial<<<dim3(NB * NT), dim3(256), 0, stream>>>(x, w_mask, pc, pm, ps);
    k_combine_mlp<<<dim3(NB), dim3(256), 0, stream>>>(pc, pm, ps, w1, b1, ln_g, ln_b, w2, b2, add);
    k_add<<<dim3(NB * CC * SB / 2048), dim3(256), 0, stream>>>(x, add, out);
}